// Round 3
// baseline (887.555 us; speedup 1.0000x reference)
//
#include <hip/hip_runtime.h>
#include <hip/hip_bf16.h>
#include <stdint.h>

// Problem constants (fixed by the reference)
#define NE      1048576     // edges
#define NNODES  65536       // B*N
#define DIMV    64          // embedding dim
#define HDIM    256         // SwiGLU hidden width

typedef __bf16 bf16x8 __attribute__((ext_vector_type(8)));
typedef float  f32x4  __attribute__((ext_vector_type(4)));

__device__ __forceinline__ unsigned short f2bf(float f) {
    union { float f; uint32_t u; } v; v.f = f;
    return (unsigned short)((v.u + 0x7fffu + ((v.u >> 16) & 1u)) >> 16);  // RNE
}

// ---------------- prep 1: node features fp32 -> bf16 table ----------------
__global__ void prep_x_kernel(const float* __restrict__ x, unsigned short* __restrict__ xb) {
    int i = blockIdx.x * blockDim.x + threadIdx.x;
    const int total = NNODES * DIMV / 4;
    for (; i < total; i += gridDim.x * blockDim.x) {
        float4 v = ((const float4*)x)[i];
        ushort4 o;
        o.x = f2bf(v.x); o.y = f2bf(v.y); o.z = f2bf(v.z); o.w = f2bf(v.w);
        ((ushort4*)xb)[i] = o;
    }
}

// ------- prep 2: weights -> transposed, XOR-swizzled bf16 LDS images -------
// Per matrix 65536 B: column h (0..255), 16B chunk cc (0..15) holding W[k][h]
// for k = cc*8..cc*8+7, at byte h*256 + ((cc*16) ^ ((h&7)<<4)).
// w_out is folded into Wi: wi'[k][h] = wi[k][h] * wo[h].
__global__ void prep_w_kernel(const float* __restrict__ wg, const float* __restrict__ wi,
                              const float* __restrict__ wo, unsigned short* __restrict__ img) {
    int t = blockIdx.x * blockDim.x + threadIdx.x;
    if (t >= 2 * HDIM * 16) return;
    int mat = t >> 12;
    int h   = (t >> 4) & 255;
    int cc  = t & 15;
    const float* w = mat ? wi : wg;
    float scale = mat ? wo[h] : 1.0f;
    unsigned short tmp[8] __attribute__((aligned(16)));
    #pragma unroll
    for (int j = 0; j < 8; ++j)
        tmp[j] = f2bf(w[(cc * 8 + j) * HDIM + h] * scale);
    int byteoff = mat * 65536 + h * 256 + ((cc * 16) ^ ((h & 7) << 4));
    *(uint4*)((char*)img + byteoff) = *(const uint4*)tmp;
}

// ---------------- main: fused gather + dual GEMM + SwiGLU + reduce ----------------
// 512 threads (8 waves), M_REP=8 -> 128 edges/wave, 1024 edges/block, grid=NE/1024.
// Full Wg+Wi' (bf16, transposed, swizzled) resident in 128 KiB LDS.
// LDS caps occupancy at 2 waves/EU -> pin it (waves_per_eu(2,2)) for the 256-reg budget.
#define M_REP 8
#define EDGES_PER_BLOCK (8 * 16 * M_REP)   // 1024
__global__ __attribute__((amdgpu_flat_work_group_size(512, 512), amdgpu_waves_per_eu(2, 2)))
void edge_swiglu_kernel(
    const unsigned short* __restrict__ xb,
    const unsigned short* __restrict__ wimg,
    const int* __restrict__ eidx,
    float* __restrict__ out)
{
    __shared__ char wlds[131072];

    const int tid  = threadIdx.x;
    const int lane = tid & 63;
    const int wave = tid >> 6;
    const int r = lane & 15;       // A row (edge) / B col (h) selector
    const int q = lane >> 4;       // k-group selector

    const int eb = blockIdx.x * EDGES_PER_BLOCK + wave * (16 * M_REP);

    // gather A fragments first (32 independent 16B loads; latency hides under staging)
    // A-frag layout (16x16x32): row = lane&15, k = (lane>>4)*8 + j
    bf16x8 a[M_REP][4];
    #pragma unroll
    for (int m = 0; m < M_REP; ++m) {
        int e  = eb + m * 16 + r;
        int sc = eidx[e];
        int gl = eidx[NE + e];
        #pragma unroll
        for (int ks = 0; ks < 4; ++ks) {
            int node = (ks < 2) ? sc : gl;                 // k<64 -> scope, else goal
            const unsigned short* p = xb + node * DIMV + (ks & 1) * 32 + q * 8;
            a[m][ks] = *(const bf16x8*)p;
        }
    }

    // stage pre-swizzled weight images -> LDS (linear b128 copy)
    {
        const uint4* src = (const uint4*)wimg;
        uint4* dst = (uint4*)wlds;
        #pragma unroll
        for (int i = 0; i < 16; ++i) {
            int idx = tid + i * 512;
            dst[idx] = src[idx];
        }
    }

    float part[M_REP][4];
    #pragma unroll
    for (int m = 0; m < M_REP; ++m)
        #pragma unroll
        for (int j = 0; j < 4; ++j) part[m][j] = 0.0f;

    __syncthreads();

    const int rbase = (r << 8);            // h*256 = (nf*16+r)*256 -> nf*4096 + rbase
    const int swz   = (r & 7) << 4;        // h&7 == r&7

    #pragma unroll
    for (int nf = 0; nf < 16; ++nf) {
        const int rowoff = nf * 4096 + rbase;
        const f32x4 zero = {0.0f, 0.0f, 0.0f, 0.0f};

        // load all 8 B-fragments for this nf once (32 regs), reuse across all m
        bf16x8 bg[4], bi[4];
        #pragma unroll
        for (int ks = 0; ks < 4; ++ks) {
            int cb = (ks * 64 + q * 16) ^ swz;
            bg[ks] = *(const bf16x8*)(wlds + rowoff + cb);
            bi[ks] = *(const bf16x8*)(wlds + 65536 + rowoff + cb);
        }

        // per-m: two 4-deep MFMA chains, then immediate epilogue (only 8 acc regs live)
        #pragma unroll
        for (int m = 0; m < M_REP; ++m) {
            f32x4 accG = zero, accI = zero;
            #pragma unroll
            for (int ks = 0; ks < 4; ++ks) {
                accG = __builtin_amdgcn_mfma_f32_16x16x32_bf16(a[m][ks], bg[ks], accG, 0, 0, 0);
                accI = __builtin_amdgcn_mfma_f32_16x16x32_bf16(a[m][ks], bi[ks], accI, 0, 0, 0);
            }
            #pragma unroll
            for (int j = 0; j < 4; ++j) {
                float g  = accG[j];
                float iv = accI[j];
                float e  = __builtin_amdgcn_exp2f(g * -1.44269504f);
                float s  = __builtin_amdgcn_rcpf(1.0f + e);
                part[m][j] = __builtin_fmaf(g * s, iv, part[m][j]);
            }
        }
    }

    // reduce over h (16 low lanes), store 4 edges per (q,m): D row = q*4+j
    #pragma unroll
    for (int m = 0; m < M_REP; ++m) {
        f32x4 v;
        #pragma unroll
        for (int j = 0; j < 4; ++j) {
            float s = part[m][j];
            s += __shfl_xor(s, 1);
            s += __shfl_xor(s, 2);
            s += __shfl_xor(s, 4);
            s += __shfl_xor(s, 8);
            v[j] = s;
        }
        if (r == 0)
            *(f32x4*)(out + eb + m * 16 + q * 4) = v;
    }
}

extern "C" void kernel_launch(void* const* d_in, const int* in_sizes, int n_in,
                              void* d_out, int out_size, void* d_ws, size_t ws_size,
                              hipStream_t stream) {
    const float* x   = (const float*)d_in[0];   // [65536, 64] fp32
    const float* wg  = (const float*)d_in[1];   // [128, 256] fp32
    const float* wi  = (const float*)d_in[2];   // [128, 256] fp32
    const float* wo  = (const float*)d_in[3];   // [256] fp32
    const int*   ei  = (const int*)d_in[4];     // [2, E] int
    float* out = (float*)d_out;

    unsigned short* xb   = (unsigned short*)d_ws;                       // 8 MiB bf16 node table
    unsigned short* wimg = (unsigned short*)((char*)d_ws + 8388608);    // 128 KiB weight images

    prep_x_kernel<<<1024, 256, 0, stream>>>(x, xb);
    prep_w_kernel<<<32, 256, 0, stream>>>(wg, wi, wo, wimg);
    edge_swiglu_kernel<<<NE / EDGES_PER_BLOCK, 512, 0, stream>>>(xb, wimg, ei, out);
}